// Round 11
// baseline (322.228 us; speedup 1.0000x reference)
//
#include <hip/hip_runtime.h>

// ---------------------------------------------------------------------------
// GraphSAGE 2-layer hetero (R=2) + edge dot scorer.  Round 19:
//  * agg1 restructured to QUARTER-wave per edge (the shape proven in agg2):
//    fp8 row = 128B = 16 lanes x uint2 -> ONE gather instruction covers 4
//    edges (was 1). Indices stay RFL'd SGPRs (csr[j..j+15] merges into
//    s_load_dwordx16) + 2-level cndmask per-quad select -- avoiding the
//    r12/r15 failure (per-lane index VMEM). 16 edges/iter, 8 cols/lane in
//    named scalars, shfl_xor(16|32) reduce, lanes 0-15 write uint4.
//    r18 profile: agg1 53us wave-LATENCY-bound (FETCH at compulsory floor,
//    HBM 21%, VALU 27%, occ 66%) -> shorten the per-wave chain ~4x.
//  * Everything else verbatim round 18 (LDS-B GEMMs, quarter-wave agg2,
//    CSR radix build, score, cvt/prep, workspace aliasing).
// ---------------------------------------------------------------------------

#define BW 128            // nodes per radix bucket (pow2)
#define NBK_MAX 1024
#define EPB 8192          // edges per block in radix passes

typedef __attribute__((ext_vector_type(8))) short bf16x8;
typedef __attribute__((ext_vector_type(4))) float floatx4;
typedef __attribute__((ext_vector_type(2))) float floatx2;

__device__ __forceinline__ unsigned short f2bf(float f) {
    unsigned u = __float_as_uint(f);
    unsigned r = u + 0x7FFFu + ((u >> 16) & 1u);
    return (unsigned short)(r >> 16);
}
__device__ __forceinline__ unsigned pack2(float a, float b) {
    return (unsigned)f2bf(a) | ((unsigned)f2bf(b) << 16);
}
__device__ __forceinline__ float bflo(unsigned v) { return __uint_as_float(v << 16); }
__device__ __forceinline__ float bfhi(unsigned v) { return __uint_as_float(v & 0xFFFF0000u); }
#define RFL(x) __builtin_amdgcn_readfirstlane(x)

// ---- fp8 e4m3 helpers (hw cvt when available, bit-math fallback) --------
#if defined(__has_builtin) && __has_builtin(__builtin_amdgcn_cvt_pk_f32_fp8)
__device__ __forceinline__ floatx2 fp8lo(unsigned v) {
    return __builtin_amdgcn_cvt_pk_f32_fp8((int)v, false);
}
__device__ __forceinline__ floatx2 fp8hi(unsigned v) {
    return __builtin_amdgcn_cvt_pk_f32_fp8((int)v, true);
}
#else
__device__ __forceinline__ float fp8_1(unsigned b) {
    return __uint_as_float(((b & 0x80u) << 24) | ((b & 0x7Fu) << 20)) * 0x1.0p+120f;
}
__device__ __forceinline__ floatx2 fp8lo(unsigned v) {
    floatx2 r; r.x = fp8_1(v & 0xFFu); r.y = fp8_1((v >> 8) & 0xFFu); return r;
}
__device__ __forceinline__ floatx2 fp8hi(unsigned v) {
    floatx2 r; r.x = fp8_1((v >> 16) & 0xFFu); r.y = fp8_1((v >> 24) & 0xFFu); return r;
}
#endif

#if defined(__has_builtin) && __has_builtin(__builtin_amdgcn_cvt_pk_fp8_f32)
__device__ __forceinline__ unsigned f32x4_fp8x4(float a, float b, float c, float d) {
    unsigned lo = __builtin_amdgcn_cvt_pk_fp8_f32(a, b, 0, false);
    return __builtin_amdgcn_cvt_pk_fp8_f32(c, d, lo, true);
}
__device__ __forceinline__ unsigned char f2fp8_1(float x) {
    return (unsigned char)(__builtin_amdgcn_cvt_pk_fp8_f32(x, x, 0, false) & 0xFFu);
}
#else
__device__ __forceinline__ unsigned f2fp8(float x) {
    float m = fminf(fabsf(x), 448.0f);
    unsigned u = __float_as_uint(m * 0x1.0p-120f);
    unsigned r = (u + 0x7FFFFu + ((u >> 20) & 1u)) >> 20;
    if (r > 0x7Eu) r = 0x7Eu;
    return r | ((__float_as_uint(x) >> 24) & 0x80u);
}
__device__ __forceinline__ unsigned f32x4_fp8x4(float a, float b, float c, float d) {
    return f2fp8(a) | (f2fp8(b) << 8) | (f2fp8(c) << 16) | (f2fp8(d) << 24);
}
__device__ __forceinline__ unsigned char f2fp8_1(float x) {
    return (unsigned char)f2fp8(x);
}
#endif

// ---- radix pass A: per-(r,bucket) counts --------------------------------
__global__ __launch_bounds__(256) void
bucket_count_kernel(const int* __restrict__ edges, int* __restrict__ bcnt,
                    int NBK, int E)
{
    __shared__ int cnt[2 * NBK_MAX];
    const int rbT = 2 * NBK;
    const int t = threadIdx.x;
    for (int k = t; k < rbT; k += 256) cnt[k] = 0;
    __syncthreads();
    long long start = (long long)blockIdx.x * EPB;
    long long twoE = 2LL * E;
    for (int u = 0; u < EPB / 256; ++u) {
        long long idx = start + u * 256 + t;
        if (idx < twoE) {
            int r = idx >= E;
            int e = (int)(idx - (long long)r * E);
            int d = edges[(size_t)r * 2 * E + E + e];
            atomicAdd(&cnt[r * NBK + (d >> 7)], 1);
        }
    }
    __syncthreads();
    for (int k = t; k < rbT; k += 256)
        if (cnt[k]) atomicAdd(&bcnt[k], cnt[k]);
}

// ---- radix pass B: exclusive scan of bucket counts ----------------------
__global__ __launch_bounds__(1024) void
bucket_scan_kernel(const int* __restrict__ bcnt, int* __restrict__ bko,
                   int rbT, int twoE)
{
    __shared__ int sm[1024];
    int t = threadIdx.x;
    int v = (t < rbT) ? bcnt[t] : 0;
    sm[t] = v;
    __syncthreads();
    for (int s = 1; s < 1024; s <<= 1) {
        int u = (t >= s) ? sm[t - s] : 0;
        __syncthreads();
        sm[t] += u;
        __syncthreads();
    }
    if (t < rbT) bko[t] = sm[t] - v;
    if (t == 0) bko[rbT] = twoE;
}

// ---- radix pass C: partition into bucket-grouped (src,dst) pairs --------
__global__ __launch_bounds__(256) void
partition_kernel(const int* __restrict__ edges, const int* __restrict__ bko,
                 int* __restrict__ gcur, uint2* __restrict__ staging,
                 int NBK, int E)
{
    __shared__ int cnt[2 * NBK_MAX];
    __shared__ int base[2 * NBK_MAX];
    const int rbT = 2 * NBK;
    const int t = threadIdx.x;
    for (int k = t; k < rbT; k += 256) cnt[k] = 0;
    __syncthreads();
    long long start = (long long)blockIdx.x * EPB;
    long long twoE = 2LL * E;
    for (int u = 0; u < EPB / 256; ++u) {
        long long idx = start + u * 256 + t;
        if (idx < twoE) {
            int r = idx >= E;
            int e = (int)(idx - (long long)r * E);
            int d = edges[(size_t)r * 2 * E + E + e];
            atomicAdd(&cnt[r * NBK + (d >> 7)], 1);
        }
    }
    __syncthreads();
    for (int k = t; k < rbT; k += 256) {
        int c0 = cnt[k];
        if (c0) base[k] = bko[k] + atomicAdd(&gcur[k], c0);
        cnt[k] = 0;
    }
    __syncthreads();
    for (int u = 0; u < EPB / 256; ++u) {
        long long idx = start + u * 256 + t;
        if (idx < twoE) {
            int r = idx >= E;
            int e = (int)(idx - (long long)r * E);
            int s = edges[(size_t)r * 2 * E + e];
            int d = edges[(size_t)r * 2 * E + E + e];
            int rb = r * NBK + (d >> 7);
            int pos = atomicAdd(&cnt[rb], 1);
            staging[(size_t)base[rb] + pos] = make_uint2((unsigned)s, (unsigned)d);
        }
    }
}

// ---- radix pass D: per-bucket node hist/scan -> off[] and csr[] ----------
__global__ __launch_bounds__(256) void
bucket_csr_kernel(const uint2* __restrict__ staging, const int* __restrict__ bko,
                  int* __restrict__ csr, int* __restrict__ off,
                  int NBK, int N)
{
    __shared__ int hist[BW], excl[BW], cur[BW], sc[BW];
    const int rb = blockIdx.x;
    const int r = rb / NBK;
    const int b = rb % NBK;
    const int node0 = b * BW;
    const int nn = min(BW, N - node0);
    const int cbase = bko[rb];
    const int c = bko[rb + 1] - cbase;
    const int t = threadIdx.x;

    if (t < BW) { hist[t] = 0; cur[t] = 0; }
    __syncthreads();
    for (int k = t; k < c; k += 256)
        atomicAdd(&hist[(int)staging[(size_t)cbase + k].y - node0], 1);
    __syncthreads();
    if (t < BW) sc[t] = hist[t];
    __syncthreads();
    for (int s = 1; s < BW; s <<= 1) {
        int v = (t < BW && t >= s) ? sc[t - s] : 0;
        __syncthreads();
        if (t < BW) sc[t] += v;
        __syncthreads();
    }
    if (t < BW) excl[t] = sc[t] - hist[t];
    if (t < nn) off[(size_t)r * N + node0 + t] = cbase + excl[t];
    __syncthreads();
    for (int k = t; k < c; k += 256) {
        uint2 pr = staging[(size_t)cbase + k];
        int l = (int)pr.y - node0;
        int pos = atomicAdd(&cur[l], 1);
        csr[(size_t)cbase + excl[l] + pos] = (int)pr.x;
    }
}

// ---- f32 -> bf16 [N,128] + fp8 [N,128] ----------------------------------
__global__ void cvt_kernel(const float* __restrict__ in,
                           unsigned short* __restrict__ o,
                           unsigned char* __restrict__ o8, int n4)
{
    int t = blockIdx.x * blockDim.x + threadIdx.x;
    if (t >= n4) return;
    float4 v = ((const float4*)in)[t];
    ushort4 r;
    r.x = f2bf(v.x); r.y = f2bf(v.y); r.z = f2bf(v.z); r.w = f2bf(v.w);
    ((ushort4*)o)[t] = r;
    ((unsigned*)o8)[t] = f32x4_fp8x4(v.x, v.y, v.z, v.w);
}

// ---- weight prep: combined-Wself / Wn -> bf16 W^T rows, biases ----------
__global__ void prep_kernel(const float* __restrict__ Ws1, const float* __restrict__ Wn1,
                            const float* __restrict__ b1,
                            const float* __restrict__ Ws2, const float* __restrict__ Wn2,
                            const float* __restrict__ b2,
                            unsigned short* __restrict__ WT1z, unsigned short* __restrict__ WT1a,
                            unsigned short* __restrict__ WT1b, float* __restrict__ bc1,
                            unsigned short* __restrict__ WT2z, unsigned short* __restrict__ WT2a,
                            unsigned short* __restrict__ WT2b, float* __restrict__ bc2)
{
    int t = blockIdx.x * blockDim.x + threadIdx.x;
    if (t < 16384) {                 // layer 1: [n][k] <- [k][n], n,k < 128
        int n = t >> 7, k = t & 127;
        int in = k * 128 + n;
        WT1z[t] = f2bf(Ws1[in] + Ws1[16384 + in]);
        WT1a[t] = f2bf(Wn1[in]);
        WT1b[t] = f2bf(Wn1[16384 + in]);
    }
    if (t < 8192) {                  // layer 2: n < 64, k < 128
        int n = t >> 7, k = t & 127;
        int in = k * 64 + n;
        WT2z[t] = f2bf(Ws2[in] + Ws2[8192 + in]);
        WT2a[t] = f2bf(Wn2[in]);
        WT2b[t] = f2bf(Wn2[8192 + in]);
    }
    if (t < 128) bc1[t] = b1[t] + b1[128 + t];
    if (t < 64)  bc2[t] = b2[t] + b2[64 + t];
}

// ---- agg L1: quarter-wave per edge, fp8 128B rows, 16 edges/iter --------
// 16 lanes x uint2 (8 fp8 cols) = one row per quarter -> 4 edges per
// gather instruction. Indices RFL'd (s_load_dwordx16) + cndmask select.
__global__ __launch_bounds__(256) void
agg1_kernel(const unsigned char* __restrict__ xb8,
            const int* __restrict__ csr, const int* __restrict__ off,
            unsigned short* __restrict__ m0, unsigned short* __restrict__ m1,
            int N, int twoE)
{
    int w = blockIdx.x * 4 + (threadIdx.x >> 6);
    int lane = threadIdx.x & 63;
    if (w >= N) return;
    const int q = lane >> 4;                 // edge slot 0..3
    const int col = (lane & 15) * 8;         // 8 fp8 cols per lane
    const unsigned char* xc = xb8 + col;

    float a0 = 0.f, a1 = 0.f, a2 = 0.f, a3 = 0.f;
    float a4 = 0.f, a5 = 0.f, a6 = 0.f, a7 = 0.f;   // rel0
    float b0 = 0.f, b1 = 0.f, b2 = 0.f, b3 = 0.f;
    float b4 = 0.f, b5 = 0.f, b6 = 0.f, b7 = 0.f;   // rel1

    // ---- relation 0 ----
    int o0 = RFL(off[w]);
    int o1 = RFL(off[w + 1]);
    int d0 = o1 - o0;
    int j = o0;
    for (; j + 15 < o1; j += 16) {
        int s0 = RFL(csr[j]);      int s1 = RFL(csr[j + 1]);
        int s2 = RFL(csr[j + 2]);  int s3 = RFL(csr[j + 3]);
        int s4 = RFL(csr[j + 4]);  int s5 = RFL(csr[j + 5]);
        int s6 = RFL(csr[j + 6]);  int s7 = RFL(csr[j + 7]);
        int s8 = RFL(csr[j + 8]);  int s9 = RFL(csr[j + 9]);
        int sa = RFL(csr[j + 10]); int sb = RFL(csr[j + 11]);
        int sc = RFL(csr[j + 12]); int sd = RFL(csr[j + 13]);
        int se = RFL(csr[j + 14]); int sf = RFL(csr[j + 15]);
        int rA, rB, rw;
        rA = (q & 1) ? s1 : s0; rB = (q & 1) ? s3 : s2; rw = (q & 2) ? rB : rA;
        uint2 v0 = *(const uint2*)(xc + (size_t)rw * 128);
        rA = (q & 1) ? s5 : s4; rB = (q & 1) ? s7 : s6; rw = (q & 2) ? rB : rA;
        uint2 v1 = *(const uint2*)(xc + (size_t)rw * 128);
        rA = (q & 1) ? s9 : s8; rB = (q & 1) ? sb : sa; rw = (q & 2) ? rB : rA;
        uint2 v2 = *(const uint2*)(xc + (size_t)rw * 128);
        rA = (q & 1) ? sd : sc; rB = (q & 1) ? sf : se; rw = (q & 2) ? rB : rA;
        uint2 v3 = *(const uint2*)(xc + (size_t)rw * 128);
        floatx2 p;
        p = fp8lo(v0.x); a0 += p.x; a1 += p.y;
        p = fp8hi(v0.x); a2 += p.x; a3 += p.y;
        p = fp8lo(v0.y); a4 += p.x; a5 += p.y;
        p = fp8hi(v0.y); a6 += p.x; a7 += p.y;
        p = fp8lo(v1.x); a0 += p.x; a1 += p.y;
        p = fp8hi(v1.x); a2 += p.x; a3 += p.y;
        p = fp8lo(v1.y); a4 += p.x; a5 += p.y;
        p = fp8hi(v1.y); a6 += p.x; a7 += p.y;
        p = fp8lo(v2.x); a0 += p.x; a1 += p.y;
        p = fp8hi(v2.x); a2 += p.x; a3 += p.y;
        p = fp8lo(v2.y); a4 += p.x; a5 += p.y;
        p = fp8hi(v2.y); a6 += p.x; a7 += p.y;
        p = fp8lo(v3.x); a0 += p.x; a1 += p.y;
        p = fp8hi(v3.x); a2 += p.x; a3 += p.y;
        p = fp8lo(v3.y); a4 += p.x; a5 += p.y;
        p = fp8hi(v3.y); a6 += p.x; a7 += p.y;
    }
    for (; j + 3 < o1; j += 4) {
        int row = csr[j + q];
        uint2 v = *(const uint2*)(xc + (size_t)row * 128);
        floatx2 p;
        p = fp8lo(v.x); a0 += p.x; a1 += p.y;
        p = fp8hi(v.x); a2 += p.x; a3 += p.y;
        p = fp8lo(v.y); a4 += p.x; a5 += p.y;
        p = fp8hi(v.y); a6 += p.x; a7 += p.y;
    }
    if (j < o1 && q < o1 - j) {
        int row = csr[j + q];
        uint2 v = *(const uint2*)(xc + (size_t)row * 128);
        floatx2 p;
        p = fp8lo(v.x); a0 += p.x; a1 += p.y;
        p = fp8hi(v.x); a2 += p.x; a3 += p.y;
        p = fp8lo(v.y); a4 += p.x; a5 += p.y;
        p = fp8hi(v.y); a6 += p.x; a7 += p.y;
    }

    // ---- relation 1 ----
    int pn = N + w;
    o0 = RFL(off[pn]);
    o1 = (pn + 1 < 2 * N) ? RFL(off[pn + 1]) : twoE;
    int d1 = o1 - o0;
    j = o0;
    for (; j + 15 < o1; j += 16) {
        int s0 = RFL(csr[j]);      int s1 = RFL(csr[j + 1]);
        int s2 = RFL(csr[j + 2]);  int s3 = RFL(csr[j + 3]);
        int s4 = RFL(csr[j + 4]);  int s5 = RFL(csr[j + 5]);
        int s6 = RFL(csr[j + 6]);  int s7 = RFL(csr[j + 7]);
        int s8 = RFL(csr[j + 8]);  int s9 = RFL(csr[j + 9]);
        int sa = RFL(csr[j + 10]); int sb = RFL(csr[j + 11]);
        int sc = RFL(csr[j + 12]); int sd = RFL(csr[j + 13]);
        int se = RFL(csr[j + 14]); int sf = RFL(csr[j + 15]);
        int rA, rB, rw;
        rA = (q & 1) ? s1 : s0; rB = (q & 1) ? s3 : s2; rw = (q & 2) ? rB : rA;
        uint2 v0 = *(const uint2*)(xc + (size_t)rw * 128);
        rA = (q & 1) ? s5 : s4; rB = (q & 1) ? s7 : s6; rw = (q & 2) ? rB : rA;
        uint2 v1 = *(const uint2*)(xc + (size_t)rw * 128);
        rA = (q & 1) ? s9 : s8; rB = (q & 1) ? sb : sa; rw = (q & 2) ? rB : rA;
        uint2 v2 = *(const uint2*)(xc + (size_t)rw * 128);
        rA = (q & 1) ? sd : sc; rB = (q & 1) ? sf : se; rw = (q & 2) ? rB : rA;
        uint2 v3 = *(const uint2*)(xc + (size_t)rw * 128);
        floatx2 p;
        p = fp8lo(v0.x); b0 += p.x; b1 += p.y;
        p = fp8hi(v0.x); b2 += p.x; b3 += p.y;
        p = fp8lo(v0.y); b4 += p.x; b5 += p.y;
        p = fp8hi(v0.y); b6 += p.x; b7 += p.y;
        p = fp8lo(v1.x); b0 += p.x; b1 += p.y;
        p = fp8hi(v1.x); b2 += p.x; b3 += p.y;
        p = fp8lo(v1.y); b4 += p.x; b5 += p.y;
        p = fp8hi(v1.y); b6 += p.x; b7 += p.y;
        p = fp8lo(v2.x); b0 += p.x; b1 += p.y;
        p = fp8hi(v2.x); b2 += p.x; b3 += p.y;
        p = fp8lo(v2.y); b4 += p.x; b5 += p.y;
        p = fp8hi(v2.y); b6 += p.x; b7 += p.y;
        p = fp8lo(v3.x); b0 += p.x; b1 += p.y;
        p = fp8hi(v3.x); b2 += p.x; b3 += p.y;
        p = fp8lo(v3.y); b4 += p.x; b5 += p.y;
        p = fp8hi(v3.y); b6 += p.x; b7 += p.y;
    }
    for (; j + 3 < o1; j += 4) {
        int row = csr[j + q];
        uint2 v = *(const uint2*)(xc + (size_t)row * 128);
        floatx2 p;
        p = fp8lo(v.x); b0 += p.x; b1 += p.y;
        p = fp8hi(v.x); b2 += p.x; b3 += p.y;
        p = fp8lo(v.y); b4 += p.x; b5 += p.y;
        p = fp8hi(v.y); b6 += p.x; b7 += p.y;
    }
    if (j < o1 && q < o1 - j) {
        int row = csr[j + q];
        uint2 v = *(const uint2*)(xc + (size_t)row * 128);
        floatx2 p;
        p = fp8lo(v.x); b0 += p.x; b1 += p.y;
        p = fp8hi(v.x); b2 += p.x; b3 += p.y;
        p = fp8lo(v.y); b4 += p.x; b5 += p.y;
        p = fp8hi(v.y); b6 += p.x; b7 += p.y;
    }

    // cross-quarter reduce
    a0 += __shfl_xor(a0, 16); a1 += __shfl_xor(a1, 16);
    a2 += __shfl_xor(a2, 16); a3 += __shfl_xor(a3, 16);
    a4 += __shfl_xor(a4, 16); a5 += __shfl_xor(a5, 16);
    a6 += __shfl_xor(a6, 16); a7 += __shfl_xor(a7, 16);
    b0 += __shfl_xor(b0, 16); b1 += __shfl_xor(b1, 16);
    b2 += __shfl_xor(b2, 16); b3 += __shfl_xor(b3, 16);
    b4 += __shfl_xor(b4, 16); b5 += __shfl_xor(b5, 16);
    b6 += __shfl_xor(b6, 16); b7 += __shfl_xor(b7, 16);
    a0 += __shfl_xor(a0, 32); a1 += __shfl_xor(a1, 32);
    a2 += __shfl_xor(a2, 32); a3 += __shfl_xor(a3, 32);
    a4 += __shfl_xor(a4, 32); a5 += __shfl_xor(a5, 32);
    a6 += __shfl_xor(a6, 32); a7 += __shfl_xor(a7, 32);
    b0 += __shfl_xor(b0, 32); b1 += __shfl_xor(b1, 32);
    b2 += __shfl_xor(b2, 32); b3 += __shfl_xor(b3, 32);
    b4 += __shfl_xor(b4, 32); b5 += __shfl_xor(b5, 32);
    b6 += __shfl_xor(b6, 32); b7 += __shfl_xor(b7, 32);
    if (q == 0) {
        float inv0 = 1.0f / fmaxf((float)d0, 1.0f);
        float inv1 = 1.0f / fmaxf((float)d1, 1.0f);
        uint4 u0, u1;
        u0.x = pack2(a0 * inv0, a1 * inv0);
        u0.y = pack2(a2 * inv0, a3 * inv0);
        u0.z = pack2(a4 * inv0, a5 * inv0);
        u0.w = pack2(a6 * inv0, a7 * inv0);
        u1.x = pack2(b0 * inv1, b1 * inv1);
        u1.y = pack2(b2 * inv1, b3 * inv1);
        u1.z = pack2(b4 * inv1, b5 * inv1);
        u1.w = pack2(b6 * inv1, b7 * inv1);
        *(uint4*)(m0 + (size_t)w * 128 + col) = u0;
        *(uint4*)(m1 + (size_t)w * 128 + col) = u1;
    }
}

// ---- B-frag read from swizzled LDS --------------------------------------
__device__ __forceinline__ bf16x8 bs_read(const unsigned short* Bs, int mat,
                                          int c, int s, int quad) {
    unsigned byte = (unsigned)(mat * 16384 + c * 256 + s * 64 + quad * 16);
    byte ^= (unsigned)((c & 7) << 4);
    return *(const bf16x8*)((const char*)Bs + byte);
}

// ---- fused layer-1 GEMM v3: B in swizzled LDS, A per-lane, 512 thr ------
__global__ __launch_bounds__(512) void
gemm1_fused_kernel(const unsigned short* __restrict__ xb,
                   const unsigned short* __restrict__ m0,
                   const unsigned short* __restrict__ m1,
                   const unsigned short* __restrict__ WTz,
                   const unsigned short* __restrict__ WTa,
                   const unsigned short* __restrict__ WTb,
                   const float* __restrict__ bias,
                   unsigned short* __restrict__ h1b, int N)
{
    __shared__ unsigned short Bs[3 * 64 * 128];   // 48KB, XOR-swizzled

    const int tid = threadIdx.x;
    const int wave = tid >> 6;        // 0..7
    const int lane = tid & 63;
    const int m = lane & 15;
    const int quad = lane >> 4;
    const int colbase = blockIdx.y * 64;

    // stage B coalesced: 6 x uint4 per thread (48KB total)
#pragma unroll
    for (int i = 0; i < 6; ++i) {
        int o = (i * 512 + tid) * 8;          // ushort linear index
        int mat = o >> 13;
        int rem = o & 8191;
        int c = rem >> 7;
        int k = rem & 127;
        const unsigned short* src = (mat == 0) ? WTz : ((mat == 1) ? WTa : WTb);
        uint4 v = *(const uint4*)(src + (size_t)(colbase + c) * 128 + k);
        unsigned byte = (unsigned)(o * 2) ^ (unsigned)((c & 7) << 4);
        *(uint4*)((char*)Bs + byte) = v;
    }
    __syncthreads();

    floatx4 acc[4];
    const floatx4 z4 = {0.f, 0.f, 0.f, 0.f};
#pragma unroll
    for (int t = 0; t < 4; ++t) acc[t] = z4;

    int arow = blockIdx.x * 128 + wave * 16 + m;
    if (arow >= N) arow = N - 1;
    const size_t ab = (size_t)arow * 128 + quad * 8;

    bf16x8 ax0 = *(const bf16x8*)(xb + ab);
    bf16x8 ax1 = *(const bf16x8*)(xb + ab + 32);
    bf16x8 ax2 = *(const bf16x8*)(xb + ab + 64);
    bf16x8 ax3 = *(const bf16x8*)(xb + ab + 96);
    bf16x8 a00 = *(const bf16x8*)(m0 + ab);
    bf16x8 a01 = *(const bf16x8*)(m0 + ab + 32);
    bf16x8 a02 = *(const bf16x8*)(m0 + ab + 64);
    bf16x8 a03 = *(const bf16x8*)(m0 + ab + 96);
    bf16x8 a10 = *(const bf16x8*)(m1 + ab);
    bf16x8 a11 = *(const bf16x8*)(m1 + ab + 32);
    bf16x8 a12 = *(const bf16x8*)(m1 + ab + 64);
    bf16x8 a13 = *(const bf16x8*)(m1 + ab + 96);

#pragma unroll
    for (int t = 0; t < 4; ++t) {
        const int c = t * 16 + m;
        acc[t] = __builtin_amdgcn_mfma_f32_16x16x32_bf16(
            ax0, bs_read(Bs, 0, c, 0, quad), acc[t], 0, 0, 0);
        acc[t] = __builtin_amdgcn_mfma_f32_16x16x32_bf16(
            a00, bs_read(Bs, 1, c, 0, quad), acc[t], 0, 0, 0);
        acc[t] = __builtin_amdgcn_mfma_f32_16x16x32_bf16(
            a10, bs_read(Bs, 2, c, 0, quad), acc[t], 0, 0, 0);
        acc[t] = __builtin_amdgcn_mfma_f32_16x16x32_bf16(
            ax1, bs_read(Bs, 0, c, 1, quad), acc[t], 0, 0, 0);
        acc[t] = __builtin_amdgcn_mfma_f32_16x16x32_bf16(
            a01, bs_read(Bs, 1, c, 1, quad), acc[t], 0, 0, 0);
        acc[t] = __builtin_amdgcn_mfma_f32_16x16x32_bf16(
            a11, bs_read(Bs, 2, c, 1, quad), acc[t], 0, 0, 0);
        acc[t] = __builtin_amdgcn_mfma_f32_16x16x32_bf16(
            ax2, bs_read(Bs, 0, c, 2, quad), acc[t], 0, 0, 0);
        acc[t] = __builtin_amdgcn_mfma_f32_16x16x32_bf16(
            a02, bs_read(Bs, 1, c, 2, quad), acc[t], 0, 0, 0);
        acc[t] = __builtin_amdgcn_mfma_f32_16x16x32_bf16(
            a12, bs_read(Bs, 2, c, 2, quad), acc[t], 0, 0, 0);
        acc[t] = __builtin_amdgcn_mfma_f32_16x16x32_bf16(
            ax3, bs_read(Bs, 0, c, 3, quad), acc[t], 0, 0, 0);
        acc[t] = __builtin_amdgcn_mfma_f32_16x16x32_bf16(
            a03, bs_read(Bs, 1, c, 3, quad), acc[t], 0, 0, 0);
        acc[t] = __builtin_amdgcn_mfma_f32_16x16x32_bf16(
            a13, bs_read(Bs, 2, c, 3, quad), acc[t], 0, 0, 0);
    }

    // direct store: row = base + quad*4+i, col = colbase+t*16+m
    const int gr0 = blockIdx.x * 128 + wave * 16 + quad * 4;
#pragma unroll
    for (int t = 0; t < 4; ++t) {
        int colg = colbase + t * 16 + m;
        float bv = bias[colg];
#pragma unroll
        for (int i = 0; i < 4; ++i) {
            int gr = gr0 + i;
            if (gr < N)
                h1b[(size_t)gr * 128 + colg] = f2bf(fmaxf(acc[t][i] + bv, 0.0f));
        }
    }
}

// ---- fused layer-2 GEMM v3: B in swizzled LDS (48KB), 512 thr -----------
__global__ __launch_bounds__(512) void
gemm2_fused_kernel(const unsigned short* __restrict__ Ab,
                   const unsigned short* __restrict__ WTz,
                   const unsigned short* __restrict__ WTa,
                   const unsigned short* __restrict__ WTb,
                   const float* __restrict__ bias,
                   float* __restrict__ zf,
                   unsigned char* __restrict__ t08, unsigned char* __restrict__ t18,
                   int N)
{
    __shared__ unsigned short Bs[3 * 64 * 128];   // 48KB, XOR-swizzled

    const int tid = threadIdx.x;
    const int wave = tid >> 6;
    const int lane = tid & 63;
    const int m = lane & 15;
    const int quad = lane >> 4;

#pragma unroll
    for (int i = 0; i < 6; ++i) {
        int o = (i * 512 + tid) * 8;
        int mat = o >> 13;
        int rem = o & 8191;
        int c = rem >> 7;
        int k = rem & 127;
        const unsigned short* src = (mat == 0) ? WTz : ((mat == 1) ? WTa : WTb);
        uint4 v = *(const uint4*)(src + (size_t)c * 128 + k);
        unsigned byte = (unsigned)(o * 2) ^ (unsigned)((c & 7) << 4);
        *(uint4*)((char*)Bs + byte) = v;
    }
    __syncthreads();

    floatx4 accz[4], acca[4], accb[4];
    const floatx4 z4 = {0.f, 0.f, 0.f, 0.f};
#pragma unroll
    for (int t = 0; t < 4; ++t) { accz[t] = z4; acca[t] = z4; accb[t] = z4; }

    int arow = blockIdx.x * 128 + wave * 16 + m;
    if (arow >= N) arow = N - 1;
    const size_t ab = (size_t)arow * 128 + quad * 8;

    bf16x8 h0 = *(const bf16x8*)(Ab + ab);
    bf16x8 h1 = *(const bf16x8*)(Ab + ab + 32);
    bf16x8 h2 = *(const bf16x8*)(Ab + ab + 64);
    bf16x8 h3 = *(const bf16x8*)(Ab + ab + 96);

#pragma unroll
    for (int t = 0; t < 4; ++t) {
        const int c = t * 16 + m;
        accz[t] = __builtin_amdgcn_mfma_f32_16x16x32_bf16(
            h0, bs_read(Bs, 0, c, 0, quad), accz[t], 0, 0, 0);
        acca[t] = __builtin_amdgcn_mfma_f32_16x16x32_bf16(
            h0, bs_read(Bs, 1, c, 0, quad), acca[t], 0, 0, 0);
        accb[t] = __builtin_amdgcn_mfma_f32_16x16x32_bf16(
            h0, bs_read(Bs, 2, c, 0, quad), accb[t], 0, 0, 0);
        accz[t] = __builtin_amdgcn_mfma_f32_16x16x32_bf16(
            h1, bs_read(Bs, 0, c, 1, quad), accz[t], 0, 0, 0);
        acca[t] = __builtin_amdgcn_mfma_f32_16x16x32_bf16(
            h1, bs_read(Bs, 1, c, 1, quad), acca[t], 0, 0, 0);
        accb[t] = __builtin_amdgcn_mfma_f32_16x16x32_bf16(
            h1, bs_read(Bs, 2, c, 1, quad), accb[t], 0, 0, 0);
        accz[t] = __builtin_amdgcn_mfma_f32_16x16x32_bf16(
            h2, bs_read(Bs, 0, c, 2, quad), accz[t], 0, 0, 0);
        acca[t] = __builtin_amdgcn_mfma_f32_16x16x32_bf16(
            h2, bs_read(Bs, 1, c, 2, quad), acca[t], 0, 0, 0);
        accb[t] = __builtin_amdgcn_mfma_f32_16x16x32_bf16(
            h2, bs_read(Bs, 2, c, 2, quad), accb[t], 0, 0, 0);
        accz[t] = __builtin_amdgcn_mfma_f32_16x16x32_bf16(
            h3, bs_read(Bs, 0, c, 3, quad), accz[t], 0, 0, 0);
        acca[t] = __builtin_amdgcn_mfma_f32_16x16x32_bf16(
            h3, bs_read(Bs, 1, c, 3, quad), acca[t], 0, 0, 0);
        accb[t] = __builtin_amdgcn_mfma_f32_16x16x32_bf16(
            h3, bs_read(Bs, 2, c, 3, quad), accb[t], 0, 0, 0);
    }

    const int gr0 = blockIdx.x * 128 + wave * 16 + quad * 4;
#pragma unroll
    for (int t = 0; t < 4; ++t) {
        int colg = t * 16 + m;
        float bv = bias[colg];
#pragma unroll
        for (int i = 0; i < 4; ++i) {
            int gr = gr0 + i;
            if (gr < N) {
                zf[(size_t)gr * 64 + colg] = accz[t][i] + bv;
                t08[(size_t)gr * 64 + colg] = f2fp8_1(acca[t][i]);
                t18[(size_t)gr * 64 + colg] = f2fp8_1(accb[t][i]);
            }
        }
    }
}

// ---- agg L2: quarter-wave per edge, fp8 64B rows, 16 edges/iter ---------
__global__ __launch_bounds__(256) void
agg2_kernel(const unsigned char* __restrict__ t08,
            const unsigned char* __restrict__ t18,
            const float* __restrict__ z2,
            const int* __restrict__ csr, const int* __restrict__ off,
            unsigned short* __restrict__ h2b, int N, int twoE)
{
    int w = blockIdx.x * 4 + (threadIdx.x >> 6);
    int lane = threadIdx.x & 63;
    if (w >= N) return;
    const int q = lane >> 4;                 // edge slot 0..3
    const int col = (lane & 15) * 4;         // 4 fp8 cols per lane
    const unsigned char* t0c = t08 + col;
    const unsigned char* t1c = t18 + col;

    float a0 = 0.f, a1 = 0.f, a2 = 0.f, a3 = 0.f;   // rel0
    float b0 = 0.f, b1 = 0.f, b2 = 0.f, b3 = 0.f;   // rel1

    // ---- relation 0 ----
    int o0 = RFL(off[w]);
    int o1 = RFL(off[w + 1]);
    int d0 = o1 - o0;
    int j = o0;
    for (; j + 15 < o1; j += 16) {
        int r0 = csr[j + q];
        int r1 = csr[j + 4 + q];
        int r2 = csr[j + 8 + q];
        int r3 = csr[j + 12 + q];
        unsigned v0 = *(const unsigned*)(t0c + (size_t)r0 * 64);
        unsigned v1 = *(const unsigned*)(t0c + (size_t)r1 * 64);
        unsigned v2 = *(const unsigned*)(t0c + (size_t)r2 * 64);
        unsigned v3 = *(const unsigned*)(t0c + (size_t)r3 * 64);
        floatx2 l0 = fp8lo(v0), h0 = fp8hi(v0);
        floatx2 l1 = fp8lo(v1), h1 = fp8hi(v1);
        floatx2 l2 = fp8lo(v2), h2 = fp8hi(v2);
        floatx2 l3 = fp8lo(v3), h3 = fp8hi(v3);
        a0 += (l0.x + l1.x) + (l2.x + l3.x);
        a1 += (l0.y + l1.y) + (l2.y + l3.y);
        a2 += (h0.x + h1.x) + (h2.x + h3.x);
        a3 += (h0.y + h1.y) + (h2.y + h3.y);
    }
    for (; j + 3 < o1; j += 4) {
        int r = csr[j + q];
        unsigned v = *(const unsigned*)(t0c + (size_t)r * 64);
        floatx2 l = fp8lo(v), h = fp8hi(v);
        a0 += l.x; a1 += l.y; a2 += h.x; a3 += h.y;
    }
    if (j < o1 && q < o1 - j) {
        int r = csr[j + q];
        unsigned v = *(const unsigned*)(t0c + (size_t)r * 64);
        floatx2 l = fp8lo(v), h = fp8hi(v);
        a0 += l.x; a1 += l.y; a2 += h.x; a3 += h.y;
    }

    // ---- relation 1 ----
    int p = N + w;
    o0 = RFL(off[p]);
    o1 = (p + 1 < 2 * N) ? RFL(off[p + 1]) : twoE;
    int d1 = o1 - o0;
    j = o0;
    for (; j + 15 < o1; j += 16) {
        int r0 = csr[j + q];
        int r1 = csr[j + 4 + q];
        int r2 = csr[j + 8 + q];
        int r3 = csr[j + 12 + q];
        unsigned v0 = *(const unsigned*)(t1c + (size_t)r0 * 64);
        unsigned v1 = *(const unsigned*)(t1c + (size_t)r1 * 64);
        unsigned v2 = *(const unsigned*)(t1c + (size_t)r2 * 64);
        unsigned v3 = *(const unsigned*)(t1c + (size_t)r3 * 64);
        floatx2 l0 = fp8lo(v0), h0 = fp8hi(v0);
        floatx2 l1 = fp8lo(v1), h1 = fp8hi(v1);
        floatx2 l2 = fp8lo(v2), h2 = fp8hi(v2);
        floatx2 l3 = fp8lo(v3), h3 = fp8hi(v3);
        b0 += (l0.x + l1.x) + (l2.x + l3.x);
        b1 += (l0.y + l1.y) + (l2.y + l3.y);
        b2 += (h0.x + h1.x) + (h2.x + h3.x);
        b3 += (h0.y + h1.y) + (h2.y + h3.y);
    }
    for (; j + 3 < o1; j += 4) {
        int r = csr[j + q];
        unsigned v = *(const unsigned*)(t1c + (size_t)r * 64);
        floatx2 l = fp8lo(v), h = fp8hi(v);
        b0 += l.x; b1 += l.y; b2 += h.x; b3 += h.y;
    }
    if (j < o1 && q < o1 - j) {
        int r = csr[j + q];
        unsigned v = *(const unsigned*)(t1c + (size_t)r * 64);
        floatx2 l = fp8lo(v), h = fp8hi(v);
        b0 += l.x; b1 += l.y; b2 += h.x; b3 += h.y;
    }

    // cross-quarter reduce + write
    a0 += __shfl_xor(a0, 16); a1 += __shfl_xor(a1, 16);
    a2 += __shfl_xor(a2, 16); a3 += __shfl_xor(a3, 16);
    b0 += __shfl_xor(b0, 16); b1 += __shfl_xor(b1, 16);
    b2 += __shfl_xor(b2, 16); b3 += __shfl_xor(b3, 16);
    a0 += __shfl_xor(a0, 32); a1 += __shfl_xor(a1, 32);
    a2 += __shfl_xor(a2, 32); a3 += __shfl_xor(a3, 32);
    b0 += __shfl_xor(b0, 32); b1 += __shfl_xor(b1, 32);
    b2 += __shfl_xor(b2, 32); b3 += __shfl_xor(b3, 32);
    if (q == 0) {
        float inv0 = 1.0f / fmaxf((float)d0, 1.0f);
        float inv1 = 1.0f / fmaxf((float)d1, 1.0f);
        float4 z = *(const float4*)(z2 + (size_t)w * 64 + col);
        float h0v = z.x + a0 * inv0 + b0 * inv1;
        float h1v = z.y + a1 * inv0 + b1 * inv1;
        float h2v = z.z + a2 * inv0 + b2 * inv1;
        float h3v = z.w + a3 * inv0 + b3 * inv1;
        uint2 u;
        u.x = pack2(h0v, h1v);
        u.y = pack2(h2v, h3v);
        *(uint2*)(h2b + (size_t)w * 64 + col) = u;
    }
}

// ---- score (merged pos+neg): 8 lanes/edge, 128B rows, shfl reduce --------
__global__ __launch_bounds__(256) void
score_kernel(const unsigned short* __restrict__ h, // [N,64] bf16
             const int* __restrict__ edges, const int* __restrict__ neg,
             float* __restrict__ out, int E, int En)
{
    int t = blockIdx.x * blockDim.x + threadIdx.x;
    int e = t >> 3;
    int c = t & 7;
    if (e >= E + En) return;
    int sI, dI, oI;
    if (e < E) { sI = edges[e]; dI = edges[E + e]; oI = e; }
    else { int en = e - E; sI = neg[en]; dI = neg[En + en]; oI = E + en; }
    uint4 va = *(const uint4*)(h + (size_t)sI * 64 + c * 8);
    uint4 vb = *(const uint4*)(h + (size_t)dI * 64 + c * 8);
    float s = 0.0f;
    s = fmaf(bflo(va.x), bflo(vb.x), s);
    s = fmaf(bfhi(va.x), bfhi(vb.x), s);
    s = fmaf(bflo(va.y), bflo(vb.y), s);
    s = fmaf(bfhi(va.y), bfhi(vb.y), s);
    s = fmaf(bflo(va.z), bflo(vb.z), s);
    s = fmaf(bfhi(va.z), bfhi(vb.z), s);
    s = fmaf(bflo(va.w), bflo(vb.w), s);
    s = fmaf(bfhi(va.w), bfhi(vb.w), s);
    s += __shfl_xor(s, 1);
    s += __shfl_xor(s, 2);
    s += __shfl_xor(s, 4);
    if (c == 0) out[oI] = s;
}

extern "C" void kernel_launch(void* const* d_in, const int* in_sizes, int n_in,
                              void* d_out, int out_size, void* d_ws, size_t ws_size,
                              hipStream_t stream)
{
    const float* x     = (const float*)d_in[0];
    const int*   edges = (const int*)d_in[1];
    const int*   neg   = (const int*)d_in[2];
    const float* Wn1   = (const float*)d_in[3];
    const float* Ws1   = (const float*)d_in[4];
    const float* b1    = (const float*)d_in[5];
    const float* Wn2   = (const float*)d_in[6];
    const float* Ws2   = (const float*)d_in[7];
    const float* b2    = (const float*)d_in[8];
    float* out = (float*)d_out;

    const int Fin = 128, R = 2;
    const int N  = in_sizes[0] / Fin;        // 50000
    const int E  = in_sizes[1] / (R * 2);    // 800000
    const int En = in_sizes[2] / 2;          // 800000
    const int twoE = 2 * E;
    const int NBK = (N + BW - 1) / BW;       // 391
    const int rbT = 2 * NBK;

    // ---- workspace layout (aliases noted) ----
    const size_t nb128 = (size_t)N * 128 * sizeof(unsigned short);   // 12.8MB
    char* p = (char*)d_ws;

    // region0: staging [2E] (CSR build) -> xb8 [N,128] fp8 (cvt..agg1)
    //          -> z2 [N,64] f32 (gemm2..agg2). Lifetimes strictly ordered.
    uint2* staging       = (uint2*)p;
    unsigned char* xb8   = (unsigned char*)p;
    float* z2            = (float*)p;
    {
        size_t r0 = (size_t)twoE * sizeof(uint2);          // 12.8MB
        size_t r1 = (size_t)N * 64 * sizeof(float);        // 12.8MB
        size_t r2 = (size_t)N * 128;                       // 6.4MB
        size_t rm = r0 > r1 ? r0 : r1;
        if (r2 > rm) rm = r2;
        p += rm;
    }
    unsigned short* m0  = (unsigned short*)p; p += nb128;  // [N,128] mean rel0 (t08/t18 reuse)
    unsigned short* m1  = (unsigned short*)p; p += nb128;  // [N,128] mean rel1 (h2b reuse)
    unsigned short* xb  = (unsigned short*)p; p += nb128;  // [N,128] bf16 x
    unsigned short* h1b = (unsigned short*)p; p += nb128;  // [N,128] bf16 h1
    unsigned short* WT1z = (unsigned short*)p; p += 16384 * 2;
    unsigned short* WT1a = (unsigned short*)p; p += 16384 * 2;
    unsigned short* WT1b = (unsigned short*)p; p += 16384 * 2;
    unsigned short* WT2z = (unsigned short*)p; p += 8192 * 2;
    unsigned short* WT2a = (unsigned short*)p; p += 8192 * 2;
    unsigned short* WT2b = (unsigned short*)p; p += 8192 * 2;
    float* bc1 = (float*)p; p += 128 * sizeof(float);
    float* bc2 = (float*)p; p += 64 * sizeof(float);
    int* bcnt = (int*)p; p += (size_t)2 * NBK_MAX * sizeof(int);
    int* gcur = (int*)p; p += (size_t)2 * NBK_MAX * sizeof(int);
    int* bko  = (int*)p; p += ((size_t)2 * NBK_MAX + 1) * sizeof(int);
    int* off  = (int*)p; p += (size_t)2 * N * sizeof(int);
    int* csr  = (int*)p;

    unsigned char*  t08 = (unsigned char*)m0;        // [N,64] fp8
    unsigned char*  t18 = t08 + (size_t)N * 64;      // [N,64] fp8
    unsigned short* h2b = m1;                        // [N,64] bf16

    const int BS = 256;
    const int edge_blocks = (twoE + EPB - 1) / EPB;
    const int gx128 = (N + 127) / 128;

    // ---- CSR build (radix by dst bucket) ----
    hipMemsetAsync(bcnt, 0, (size_t)4 * NBK_MAX * sizeof(int), stream);
    bucket_count_kernel<<<edge_blocks, BS, 0, stream>>>(edges, bcnt, NBK, E);
    bucket_scan_kernel<<<1, 1024, 0, stream>>>(bcnt, bko, rbT, twoE);
    partition_kernel<<<edge_blocks, BS, 0, stream>>>(edges, bko, gcur, staging, NBK, E);
    bucket_csr_kernel<<<rbT, BS, 0, stream>>>(staging, bko, csr, off, NBK, N);

    // ---- prep (cvt AFTER bucket_csr: xb8 aliases dead staging) ----
    cvt_kernel<<<(N * 32 + BS - 1) / BS, BS, 0, stream>>>(x, xb, xb8, N * 32);
    prep_kernel<<<(16384 + BS - 1) / BS, BS, 0, stream>>>(
        Ws1, Wn1, b1, Ws2, Wn2, b2,
        WT1z, WT1a, WT1b, bc1, WT2z, WT2a, WT2b, bc2);

    // ---- Layer 1: fp8 aggregate (quarter-wave), then fused 3-matmul GEMM
    agg1_kernel<<<(N + 3) / 4, BS, 0, stream>>>(xb8, csr, off, m0, m1, N, twoE);
    {
        dim3 g(gx128, 2);
        gemm1_fused_kernel<<<g, 512, 0, stream>>>(xb, m0, m1, WT1z, WT1a, WT1b,
                                                  bc1, h1b, N);
    }

    // ---- Layer 2: fused transform (z2 f32, t0/t1 fp8), quarter-wave agg -
    gemm2_fused_kernel<<<gx128, 512, 0, stream>>>(h1b, WT2z, WT2a, WT2b, bc2,
                                                  z2, t08, t18, N);
    agg2_kernel<<<(N + 3) / 4, BS, 0, stream>>>(t08, t18, z2, csr, off, h2b, N, twoE);

    // ---- Scores (pos + neg in one launch) ----
    score_kernel<<<((E + En) * 8 + BS - 1) / BS, BS, 0, stream>>>(
        h2b, edges, neg, out, E, En);
}

// Round 12
// 313.073 us; speedup vs baseline: 1.0292x; 1.0292x over previous
//
#include <hip/hip_runtime.h>

// ---------------------------------------------------------------------------
// GraphSAGE 2-layer hetero (R=2) + edge dot scorer.  Round 20:
//  * agg1 index path fixed: r19's "RFL'd" csr reads were still 16 VMEM
//    broadcast loads per 16-edge iter (load + v_readfirstlane), so VMEM
//    only fell 32->20, explaining the 7% gain. Now ONE coalesced load
//    (idx = csr[j + (lane&15)], single 64B line) + 4 ds_bpermute shfl
//    distributes indices to quarters -> 5 VMEM per 16 edges (1 idx + 4
//    gathers). Accumulators are floatx2 (v_pk_add_f32, halves add VALU).
//    Quarter-wave gather shape (16 lanes x uint2 = 128B fp8 row, 4
//    edges/instr) kept from r19.
//  * Everything else verbatim round 19 (LDS-B GEMMs, quarter-wave agg2,
//    CSR radix build, score, cvt/prep, workspace aliasing).
// ---------------------------------------------------------------------------

#define BW 128            // nodes per radix bucket (pow2)
#define NBK_MAX 1024
#define EPB 8192          // edges per block in radix passes

typedef __attribute__((ext_vector_type(8))) short bf16x8;
typedef __attribute__((ext_vector_type(4))) float floatx4;
typedef __attribute__((ext_vector_type(2))) float floatx2;

__device__ __forceinline__ unsigned short f2bf(float f) {
    unsigned u = __float_as_uint(f);
    unsigned r = u + 0x7FFFu + ((u >> 16) & 1u);
    return (unsigned short)(r >> 16);
}
__device__ __forceinline__ unsigned pack2(float a, float b) {
    return (unsigned)f2bf(a) | ((unsigned)f2bf(b) << 16);
}
__device__ __forceinline__ float bflo(unsigned v) { return __uint_as_float(v << 16); }
__device__ __forceinline__ float bfhi(unsigned v) { return __uint_as_float(v & 0xFFFF0000u); }
#define RFL(x) __builtin_amdgcn_readfirstlane(x)

// ---- fp8 e4m3 helpers (hw cvt when available, bit-math fallback) --------
#if defined(__has_builtin) && __has_builtin(__builtin_amdgcn_cvt_pk_f32_fp8)
__device__ __forceinline__ floatx2 fp8lo(unsigned v) {
    return __builtin_amdgcn_cvt_pk_f32_fp8((int)v, false);
}
__device__ __forceinline__ floatx2 fp8hi(unsigned v) {
    return __builtin_amdgcn_cvt_pk_f32_fp8((int)v, true);
}
#else
__device__ __forceinline__ float fp8_1(unsigned b) {
    return __uint_as_float(((b & 0x80u) << 24) | ((b & 0x7Fu) << 20)) * 0x1.0p+120f;
}
__device__ __forceinline__ floatx2 fp8lo(unsigned v) {
    floatx2 r; r.x = fp8_1(v & 0xFFu); r.y = fp8_1((v >> 8) & 0xFFu); return r;
}
__device__ __forceinline__ floatx2 fp8hi(unsigned v) {
    floatx2 r; r.x = fp8_1((v >> 16) & 0xFFu); r.y = fp8_1((v >> 24) & 0xFFu); return r;
}
#endif

#if defined(__has_builtin) && __has_builtin(__builtin_amdgcn_cvt_pk_fp8_f32)
__device__ __forceinline__ unsigned f32x4_fp8x4(float a, float b, float c, float d) {
    unsigned lo = __builtin_amdgcn_cvt_pk_fp8_f32(a, b, 0, false);
    return __builtin_amdgcn_cvt_pk_fp8_f32(c, d, lo, true);
}
__device__ __forceinline__ unsigned char f2fp8_1(float x) {
    return (unsigned char)(__builtin_amdgcn_cvt_pk_fp8_f32(x, x, 0, false) & 0xFFu);
}
#else
__device__ __forceinline__ unsigned f2fp8(float x) {
    float m = fminf(fabsf(x), 448.0f);
    unsigned u = __float_as_uint(m * 0x1.0p-120f);
    unsigned r = (u + 0x7FFFFu + ((u >> 20) & 1u)) >> 20;
    if (r > 0x7Eu) r = 0x7Eu;
    return r | ((__float_as_uint(x) >> 24) & 0x80u);
}
__device__ __forceinline__ unsigned f32x4_fp8x4(float a, float b, float c, float d) {
    return f2fp8(a) | (f2fp8(b) << 8) | (f2fp8(c) << 16) | (f2fp8(d) << 24);
}
__device__ __forceinline__ unsigned char f2fp8_1(float x) {
    return (unsigned char)f2fp8(x);
}
#endif

// ---- radix pass A: per-(r,bucket) counts --------------------------------
__global__ __launch_bounds__(256) void
bucket_count_kernel(const int* __restrict__ edges, int* __restrict__ bcnt,
                    int NBK, int E)
{
    __shared__ int cnt[2 * NBK_MAX];
    const int rbT = 2 * NBK;
    const int t = threadIdx.x;
    for (int k = t; k < rbT; k += 256) cnt[k] = 0;
    __syncthreads();
    long long start = (long long)blockIdx.x * EPB;
    long long twoE = 2LL * E;
    for (int u = 0; u < EPB / 256; ++u) {
        long long idx = start + u * 256 + t;
        if (idx < twoE) {
            int r = idx >= E;
            int e = (int)(idx - (long long)r * E);
            int d = edges[(size_t)r * 2 * E + E + e];
            atomicAdd(&cnt[r * NBK + (d >> 7)], 1);
        }
    }
    __syncthreads();
    for (int k = t; k < rbT; k += 256)
        if (cnt[k]) atomicAdd(&bcnt[k], cnt[k]);
}

// ---- radix pass B: exclusive scan of bucket counts ----------------------
__global__ __launch_bounds__(1024) void
bucket_scan_kernel(const int* __restrict__ bcnt, int* __restrict__ bko,
                   int rbT, int twoE)
{
    __shared__ int sm[1024];
    int t = threadIdx.x;
    int v = (t < rbT) ? bcnt[t] : 0;
    sm[t] = v;
    __syncthreads();
    for (int s = 1; s < 1024; s <<= 1) {
        int u = (t >= s) ? sm[t - s] : 0;
        __syncthreads();
        sm[t] += u;
        __syncthreads();
    }
    if (t < rbT) bko[t] = sm[t] - v;
    if (t == 0) bko[rbT] = twoE;
}

// ---- radix pass C: partition into bucket-grouped (src,dst) pairs --------
__global__ __launch_bounds__(256) void
partition_kernel(const int* __restrict__ edges, const int* __restrict__ bko,
                 int* __restrict__ gcur, uint2* __restrict__ staging,
                 int NBK, int E)
{
    __shared__ int cnt[2 * NBK_MAX];
    __shared__ int base[2 * NBK_MAX];
    const int rbT = 2 * NBK;
    const int t = threadIdx.x;
    for (int k = t; k < rbT; k += 256) cnt[k] = 0;
    __syncthreads();
    long long start = (long long)blockIdx.x * EPB;
    long long twoE = 2LL * E;
    for (int u = 0; u < EPB / 256; ++u) {
        long long idx = start + u * 256 + t;
        if (idx < twoE) {
            int r = idx >= E;
            int e = (int)(idx - (long long)r * E);
            int d = edges[(size_t)r * 2 * E + E + e];
            atomicAdd(&cnt[r * NBK + (d >> 7)], 1);
        }
    }
    __syncthreads();
    for (int k = t; k < rbT; k += 256) {
        int c0 = cnt[k];
        if (c0) base[k] = bko[k] + atomicAdd(&gcur[k], c0);
        cnt[k] = 0;
    }
    __syncthreads();
    for (int u = 0; u < EPB / 256; ++u) {
        long long idx = start + u * 256 + t;
        if (idx < twoE) {
            int r = idx >= E;
            int e = (int)(idx - (long long)r * E);
            int s = edges[(size_t)r * 2 * E + e];
            int d = edges[(size_t)r * 2 * E + E + e];
            int rb = r * NBK + (d >> 7);
            int pos = atomicAdd(&cnt[rb], 1);
            staging[(size_t)base[rb] + pos] = make_uint2((unsigned)s, (unsigned)d);
        }
    }
}

// ---- radix pass D: per-bucket node hist/scan -> off[] and csr[] ----------
__global__ __launch_bounds__(256) void
bucket_csr_kernel(const uint2* __restrict__ staging, const int* __restrict__ bko,
                  int* __restrict__ csr, int* __restrict__ off,
                  int NBK, int N)
{
    __shared__ int hist[BW], excl[BW], cur[BW], sc[BW];
    const int rb = blockIdx.x;
    const int r = rb / NBK;
    const int b = rb % NBK;
    const int node0 = b * BW;
    const int nn = min(BW, N - node0);
    const int cbase = bko[rb];
    const int c = bko[rb + 1] - cbase;
    const int t = threadIdx.x;

    if (t < BW) { hist[t] = 0; cur[t] = 0; }
    __syncthreads();
    for (int k = t; k < c; k += 256)
        atomicAdd(&hist[(int)staging[(size_t)cbase + k].y - node0], 1);
    __syncthreads();
    if (t < BW) sc[t] = hist[t];
    __syncthreads();
    for (int s = 1; s < BW; s <<= 1) {
        int v = (t < BW && t >= s) ? sc[t - s] : 0;
        __syncthreads();
        if (t < BW) sc[t] += v;
        __syncthreads();
    }
    if (t < BW) excl[t] = sc[t] - hist[t];
    if (t < nn) off[(size_t)r * N + node0 + t] = cbase + excl[t];
    __syncthreads();
    for (int k = t; k < c; k += 256) {
        uint2 pr = staging[(size_t)cbase + k];
        int l = (int)pr.y - node0;
        int pos = atomicAdd(&cur[l], 1);
        csr[(size_t)cbase + excl[l] + pos] = (int)pr.x;
    }
}

// ---- f32 -> bf16 [N,128] + fp8 [N,128] ----------------------------------
__global__ void cvt_kernel(const float* __restrict__ in,
                           unsigned short* __restrict__ o,
                           unsigned char* __restrict__ o8, int n4)
{
    int t = blockIdx.x * blockDim.x + threadIdx.x;
    if (t >= n4) return;
    float4 v = ((const float4*)in)[t];
    ushort4 r;
    r.x = f2bf(v.x); r.y = f2bf(v.y); r.z = f2bf(v.z); r.w = f2bf(v.w);
    ((ushort4*)o)[t] = r;
    ((unsigned*)o8)[t] = f32x4_fp8x4(v.x, v.y, v.z, v.w);
}

// ---- weight prep: combined-Wself / Wn -> bf16 W^T rows, biases ----------
__global__ void prep_kernel(const float* __restrict__ Ws1, const float* __restrict__ Wn1,
                            const float* __restrict__ b1,
                            const float* __restrict__ Ws2, const float* __restrict__ Wn2,
                            const float* __restrict__ b2,
                            unsigned short* __restrict__ WT1z, unsigned short* __restrict__ WT1a,
                            unsigned short* __restrict__ WT1b, float* __restrict__ bc1,
                            unsigned short* __restrict__ WT2z, unsigned short* __restrict__ WT2a,
                            unsigned short* __restrict__ WT2b, float* __restrict__ bc2)
{
    int t = blockIdx.x * blockDim.x + threadIdx.x;
    if (t < 16384) {                 // layer 1: [n][k] <- [k][n], n,k < 128
        int n = t >> 7, k = t & 127;
        int in = k * 128 + n;
        WT1z[t] = f2bf(Ws1[in] + Ws1[16384 + in]);
        WT1a[t] = f2bf(Wn1[in]);
        WT1b[t] = f2bf(Wn1[16384 + in]);
    }
    if (t < 8192) {                  // layer 2: n < 64, k < 128
        int n = t >> 7, k = t & 127;
        int in = k * 64 + n;
        WT2z[t] = f2bf(Ws2[in] + Ws2[8192 + in]);
        WT2a[t] = f2bf(Wn2[in]);
        WT2b[t] = f2bf(Wn2[8192 + in]);
    }
    if (t < 128) bc1[t] = b1[t] + b1[128 + t];
    if (t < 64)  bc2[t] = b2[t] + b2[64 + t];
}

// ---- agg L1: quarter-wave per edge, vector csr load + bpermute ----------
// Per 16-edge iter: 1 coalesced index load (csr[j+(lane&15)], one 64B
// line) + 4 __shfl broadcasts + 4 row gathers = 5 VMEM (was 20).
__global__ __launch_bounds__(256) void
agg1_kernel(const unsigned char* __restrict__ xb8,
            const int* __restrict__ csr, const int* __restrict__ off,
            unsigned short* __restrict__ m0, unsigned short* __restrict__ m1,
            int N, int twoE)
{
    int w = blockIdx.x * 4 + (threadIdx.x >> 6);
    int lane = threadIdx.x & 63;
    if (w >= N) return;
    const int q = lane >> 4;                 // edge slot 0..3
    const int li = lane & 15;
    const int col = li * 8;                  // 8 fp8 cols per lane
    const unsigned char* xc = xb8 + col;

    const floatx2 z2v = {0.f, 0.f};
    floatx2 a01 = z2v, a23 = z2v, a45 = z2v, a67 = z2v;   // rel0
    floatx2 b01 = z2v, b23 = z2v, b45 = z2v, b67 = z2v;   // rel1

    // ---- relation 0 ----
    int o0 = RFL(off[w]);
    int o1 = RFL(off[w + 1]);
    int d0 = o1 - o0;
    int j = o0;
    for (; j + 15 < o1; j += 16) {
        int idx = csr[j + li];               // 16 indices, one 64B line
        int r0 = __shfl(idx, 0 + q);
        int r1 = __shfl(idx, 4 + q);
        int r2 = __shfl(idx, 8 + q);
        int r3 = __shfl(idx, 12 + q);
        uint2 v0 = *(const uint2*)(xc + (size_t)r0 * 128);
        uint2 v1 = *(const uint2*)(xc + (size_t)r1 * 128);
        uint2 v2 = *(const uint2*)(xc + (size_t)r2 * 128);
        uint2 v3 = *(const uint2*)(xc + (size_t)r3 * 128);
        a01 += fp8lo(v0.x); a23 += fp8hi(v0.x);
        a45 += fp8lo(v0.y); a67 += fp8hi(v0.y);
        a01 += fp8lo(v1.x); a23 += fp8hi(v1.x);
        a45 += fp8lo(v1.y); a67 += fp8hi(v1.y);
        a01 += fp8lo(v2.x); a23 += fp8hi(v2.x);
        a45 += fp8lo(v2.y); a67 += fp8hi(v2.y);
        a01 += fp8lo(v3.x); a23 += fp8hi(v3.x);
        a45 += fp8lo(v3.y); a67 += fp8hi(v3.y);
    }
    for (; j + 3 < o1; j += 4) {
        int row = csr[j + q];
        uint2 v = *(const uint2*)(xc + (size_t)row * 128);
        a01 += fp8lo(v.x); a23 += fp8hi(v.x);
        a45 += fp8lo(v.y); a67 += fp8hi(v.y);
    }
    if (j < o1 && q < o1 - j) {
        int row = csr[j + q];
        uint2 v = *(const uint2*)(xc + (size_t)row * 128);
        a01 += fp8lo(v.x); a23 += fp8hi(v.x);
        a45 += fp8lo(v.y); a67 += fp8hi(v.y);
    }

    // ---- relation 1 ----
    int pn = N + w;
    o0 = RFL(off[pn]);
    o1 = (pn + 1 < 2 * N) ? RFL(off[pn + 1]) : twoE;
    int d1 = o1 - o0;
    j = o0;
    for (; j + 15 < o1; j += 16) {
        int idx = csr[j + li];
        int r0 = __shfl(idx, 0 + q);
        int r1 = __shfl(idx, 4 + q);
        int r2 = __shfl(idx, 8 + q);
        int r3 = __shfl(idx, 12 + q);
        uint2 v0 = *(const uint2*)(xc + (size_t)r0 * 128);
        uint2 v1 = *(const uint2*)(xc + (size_t)r1 * 128);
        uint2 v2 = *(const uint2*)(xc + (size_t)r2 * 128);
        uint2 v3 = *(const uint2*)(xc + (size_t)r3 * 128);
        b01 += fp8lo(v0.x); b23 += fp8hi(v0.x);
        b45 += fp8lo(v0.y); b67 += fp8hi(v0.y);
        b01 += fp8lo(v1.x); b23 += fp8hi(v1.x);
        b45 += fp8lo(v1.y); b67 += fp8hi(v1.y);
        b01 += fp8lo(v2.x); b23 += fp8hi(v2.x);
        b45 += fp8lo(v2.y); b67 += fp8hi(v2.y);
        b01 += fp8lo(v3.x); b23 += fp8hi(v3.x);
        b45 += fp8lo(v3.y); b67 += fp8hi(v3.y);
    }
    for (; j + 3 < o1; j += 4) {
        int row = csr[j + q];
        uint2 v = *(const uint2*)(xc + (size_t)row * 128);
        b01 += fp8lo(v.x); b23 += fp8hi(v.x);
        b45 += fp8lo(v.y); b67 += fp8hi(v.y);
    }
    if (j < o1 && q < o1 - j) {
        int row = csr[j + q];
        uint2 v = *(const uint2*)(xc + (size_t)row * 128);
        b01 += fp8lo(v.x); b23 += fp8hi(v.x);
        b45 += fp8lo(v.y); b67 += fp8hi(v.y);
    }

    // cross-quarter reduce
    float a0 = a01.x, a1 = a01.y, a2 = a23.x, a3 = a23.y;
    float a4 = a45.x, a5 = a45.y, a6 = a67.x, a7 = a67.y;
    float b0 = b01.x, b1 = b01.y, b2 = b23.x, b3 = b23.y;
    float b4 = b45.x, b5 = b45.y, b6 = b67.x, b7 = b67.y;
    a0 += __shfl_xor(a0, 16); a1 += __shfl_xor(a1, 16);
    a2 += __shfl_xor(a2, 16); a3 += __shfl_xor(a3, 16);
    a4 += __shfl_xor(a4, 16); a5 += __shfl_xor(a5, 16);
    a6 += __shfl_xor(a6, 16); a7 += __shfl_xor(a7, 16);
    b0 += __shfl_xor(b0, 16); b1 += __shfl_xor(b1, 16);
    b2 += __shfl_xor(b2, 16); b3 += __shfl_xor(b3, 16);
    b4 += __shfl_xor(b4, 16); b5 += __shfl_xor(b5, 16);
    b6 += __shfl_xor(b6, 16); b7 += __shfl_xor(b7, 16);
    a0 += __shfl_xor(a0, 32); a1 += __shfl_xor(a1, 32);
    a2 += __shfl_xor(a2, 32); a3 += __shfl_xor(a3, 32);
    a4 += __shfl_xor(a4, 32); a5 += __shfl_xor(a5, 32);
    a6 += __shfl_xor(a6, 32); a7 += __shfl_xor(a7, 32);
    b0 += __shfl_xor(b0, 32); b1 += __shfl_xor(b1, 32);
    b2 += __shfl_xor(b2, 32); b3 += __shfl_xor(b3, 32);
    b4 += __shfl_xor(b4, 32); b5 += __shfl_xor(b5, 32);
    b6 += __shfl_xor(b6, 32); b7 += __shfl_xor(b7, 32);
    if (q == 0) {
        float inv0 = 1.0f / fmaxf((float)d0, 1.0f);
        float inv1 = 1.0f / fmaxf((float)d1, 1.0f);
        uint4 u0, u1;
        u0.x = pack2(a0 * inv0, a1 * inv0);
        u0.y = pack2(a2 * inv0, a3 * inv0);
        u0.z = pack2(a4 * inv0, a5 * inv0);
        u0.w = pack2(a6 * inv0, a7 * inv0);
        u1.x = pack2(b0 * inv1, b1 * inv1);
        u1.y = pack2(b2 * inv1, b3 * inv1);
        u1.z = pack2(b4 * inv1, b5 * inv1);
        u1.w = pack2(b6 * inv1, b7 * inv1);
        *(uint4*)(m0 + (size_t)w * 128 + col) = u0;
        *(uint4*)(m1 + (size_t)w * 128 + col) = u1;
    }
}

// ---- B-frag read from swizzled LDS --------------------------------------
__device__ __forceinline__ bf16x8 bs_read(const unsigned short* Bs, int mat,
                                          int c, int s, int quad) {
    unsigned byte = (unsigned)(mat * 16384 + c * 256 + s * 64 + quad * 16);
    byte ^= (unsigned)((c & 7) << 4);
    return *(const bf16x8*)((const char*)Bs + byte);
}

// ---- fused layer-1 GEMM v3: B in swizzled LDS, A per-lane, 512 thr ------
__global__ __launch_bounds__(512) void
gemm1_fused_kernel(const unsigned short* __restrict__ xb,
                   const unsigned short* __restrict__ m0,
                   const unsigned short* __restrict__ m1,
                   const unsigned short* __restrict__ WTz,
                   const unsigned short* __restrict__ WTa,
                   const unsigned short* __restrict__ WTb,
                   const float* __restrict__ bias,
                   unsigned short* __restrict__ h1b, int N)
{
    __shared__ unsigned short Bs[3 * 64 * 128];   // 48KB, XOR-swizzled

    const int tid = threadIdx.x;
    const int wave = tid >> 6;        // 0..7
    const int lane = tid & 63;
    const int m = lane & 15;
    const int quad = lane >> 4;
    const int colbase = blockIdx.y * 64;

    // stage B coalesced: 6 x uint4 per thread (48KB total)
#pragma unroll
    for (int i = 0; i < 6; ++i) {
        int o = (i * 512 + tid) * 8;          // ushort linear index
        int mat = o >> 13;
        int rem = o & 8191;
        int c = rem >> 7;
        int k = rem & 127;
        const unsigned short* src = (mat == 0) ? WTz : ((mat == 1) ? WTa : WTb);
        uint4 v = *(const uint4*)(src + (size_t)(colbase + c) * 128 + k);
        unsigned byte = (unsigned)(o * 2) ^ (unsigned)((c & 7) << 4);
        *(uint4*)((char*)Bs + byte) = v;
    }
    __syncthreads();

    floatx4 acc[4];
    const floatx4 z4 = {0.f, 0.f, 0.f, 0.f};
#pragma unroll
    for (int t = 0; t < 4; ++t) acc[t] = z4;

    int arow = blockIdx.x * 128 + wave * 16 + m;
    if (arow >= N) arow = N - 1;
    const size_t ab = (size_t)arow * 128 + quad * 8;

    bf16x8 ax0 = *(const bf16x8*)(xb + ab);
    bf16x8 ax1 = *(const bf16x8*)(xb + ab + 32);
    bf16x8 ax2 = *(const bf16x8*)(xb + ab + 64);
    bf16x8 ax3 = *(const bf16x8*)(xb + ab + 96);
    bf16x8 a00 = *(const bf16x8*)(m0 + ab);
    bf16x8 a01 = *(const bf16x8*)(m0 + ab + 32);
    bf16x8 a02 = *(const bf16x8*)(m0 + ab + 64);
    bf16x8 a03 = *(const bf16x8*)(m0 + ab + 96);
    bf16x8 a10 = *(const bf16x8*)(m1 + ab);
    bf16x8 a11 = *(const bf16x8*)(m1 + ab + 32);
    bf16x8 a12 = *(const bf16x8*)(m1 + ab + 64);
    bf16x8 a13 = *(const bf16x8*)(m1 + ab + 96);

#pragma unroll
    for (int t = 0; t < 4; ++t) {
        const int c = t * 16 + m;
        acc[t] = __builtin_amdgcn_mfma_f32_16x16x32_bf16(
            ax0, bs_read(Bs, 0, c, 0, quad), acc[t], 0, 0, 0);
        acc[t] = __builtin_amdgcn_mfma_f32_16x16x32_bf16(
            a00, bs_read(Bs, 1, c, 0, quad), acc[t], 0, 0, 0);
        acc[t] = __builtin_amdgcn_mfma_f32_16x16x32_bf16(
            a10, bs_read(Bs, 2, c, 0, quad), acc[t], 0, 0, 0);
        acc[t] = __builtin_amdgcn_mfma_f32_16x16x32_bf16(
            ax1, bs_read(Bs, 0, c, 1, quad), acc[t], 0, 0, 0);
        acc[t] = __builtin_amdgcn_mfma_f32_16x16x32_bf16(
            a01, bs_read(Bs, 1, c, 1, quad), acc[t], 0, 0, 0);
        acc[t] = __builtin_amdgcn_mfma_f32_16x16x32_bf16(
            a11, bs_read(Bs, 2, c, 1, quad), acc[t], 0, 0, 0);
        acc[t] = __builtin_amdgcn_mfma_f32_16x16x32_bf16(
            ax2, bs_read(Bs, 0, c, 2, quad), acc[t], 0, 0, 0);
        acc[t] = __builtin_amdgcn_mfma_f32_16x16x32_bf16(
            a02, bs_read(Bs, 1, c, 2, quad), acc[t], 0, 0, 0);
        acc[t] = __builtin_amdgcn_mfma_f32_16x16x32_bf16(
            a12, bs_read(Bs, 2, c, 2, quad), acc[t], 0, 0, 0);
        acc[t] = __builtin_amdgcn_mfma_f32_16x16x32_bf16(
            ax3, bs_read(Bs, 0, c, 3, quad), acc[t], 0, 0, 0);
        acc[t] = __builtin_amdgcn_mfma_f32_16x16x32_bf16(
            a03, bs_read(Bs, 1, c, 3, quad), acc[t], 0, 0, 0);
        acc[t] = __builtin_amdgcn_mfma_f32_16x16x32_bf16(
            a13, bs_read(Bs, 2, c, 3, quad), acc[t], 0, 0, 0);
    }

    // direct store: row = base + quad*4+i, col = colbase+t*16+m
    const int gr0 = blockIdx.x * 128 + wave * 16 + quad * 4;
#pragma unroll
    for (int t = 0; t < 4; ++t) {
        int colg = colbase + t * 16 + m;
        float bv = bias[colg];
#pragma unroll
        for (int i = 0; i < 4; ++i) {
            int gr = gr0 + i;
            if (gr < N)
                h1b[(size_t)gr * 128 + colg] = f2bf(fmaxf(acc[t][i] + bv, 0.0f));
        }
    }
}

// ---- fused layer-2 GEMM v3: B in swizzled LDS (48KB), 512 thr -----------
__global__ __launch_bounds__(512) void
gemm2_fused_kernel(const unsigned short* __restrict__ Ab,
                   const unsigned short* __restrict__ WTz,
                   const unsigned short* __restrict__ WTa,
                   const unsigned short* __restrict__ WTb,
                   const float* __restrict__ bias,
                   float* __restrict__ zf,
                   unsigned char* __restrict__ t08, unsigned char* __restrict__ t18,
                   int N)
{
    __shared__ unsigned short Bs[3 * 64 * 128];   // 48KB, XOR-swizzled

    const int tid = threadIdx.x;
    const int wave = tid >> 6;
    const int lane = tid & 63;
    const int m = lane & 15;
    const int quad = lane >> 4;

#pragma unroll
    for (int i = 0; i < 6; ++i) {
        int o = (i * 512 + tid) * 8;
        int mat = o >> 13;
        int rem = o & 8191;
        int c = rem >> 7;
        int k = rem & 127;
        const unsigned short* src = (mat == 0) ? WTz : ((mat == 1) ? WTa : WTb);
        uint4 v = *(const uint4*)(src + (size_t)c * 128 + k);
        unsigned byte = (unsigned)(o * 2) ^ (unsigned)((c & 7) << 4);
        *(uint4*)((char*)Bs + byte) = v;
    }
    __syncthreads();

    floatx4 accz[4], acca[4], accb[4];
    const floatx4 z4 = {0.f, 0.f, 0.f, 0.f};
#pragma unroll
    for (int t = 0; t < 4; ++t) { accz[t] = z4; acca[t] = z4; accb[t] = z4; }

    int arow = blockIdx.x * 128 + wave * 16 + m;
    if (arow >= N) arow = N - 1;
    const size_t ab = (size_t)arow * 128 + quad * 8;

    bf16x8 h0 = *(const bf16x8*)(Ab + ab);
    bf16x8 h1 = *(const bf16x8*)(Ab + ab + 32);
    bf16x8 h2 = *(const bf16x8*)(Ab + ab + 64);
    bf16x8 h3 = *(const bf16x8*)(Ab + ab + 96);

#pragma unroll
    for (int t = 0; t < 4; ++t) {
        const int c = t * 16 + m;
        accz[t] = __builtin_amdgcn_mfma_f32_16x16x32_bf16(
            h0, bs_read(Bs, 0, c, 0, quad), accz[t], 0, 0, 0);
        acca[t] = __builtin_amdgcn_mfma_f32_16x16x32_bf16(
            h0, bs_read(Bs, 1, c, 0, quad), acca[t], 0, 0, 0);
        accb[t] = __builtin_amdgcn_mfma_f32_16x16x32_bf16(
            h0, bs_read(Bs, 2, c, 0, quad), accb[t], 0, 0, 0);
        accz[t] = __builtin_amdgcn_mfma_f32_16x16x32_bf16(
            h1, bs_read(Bs, 0, c, 1, quad), accz[t], 0, 0, 0);
        acca[t] = __builtin_amdgcn_mfma_f32_16x16x32_bf16(
            h1, bs_read(Bs, 1, c, 1, quad), acca[t], 0, 0, 0);
        accb[t] = __builtin_amdgcn_mfma_f32_16x16x32_bf16(
            h1, bs_read(Bs, 2, c, 1, quad), accb[t], 0, 0, 0);
        accz[t] = __builtin_amdgcn_mfma_f32_16x16x32_bf16(
            h2, bs_read(Bs, 0, c, 2, quad), accz[t], 0, 0, 0);
        acca[t] = __builtin_amdgcn_mfma_f32_16x16x32_bf16(
            h2, bs_read(Bs, 1, c, 2, quad), acca[t], 0, 0, 0);
        accb[t] = __builtin_amdgcn_mfma_f32_16x16x32_bf16(
            h2, bs_read(Bs, 2, c, 2, quad), accb[t], 0, 0, 0);
        accz[t] = __builtin_amdgcn_mfma_f32_16x16x32_bf16(
            h3, bs_read(Bs, 0, c, 3, quad), accz[t], 0, 0, 0);
        acca[t] = __builtin_amdgcn_mfma_f32_16x16x32_bf16(
            h3, bs_read(Bs, 1, c, 3, quad), acca[t], 0, 0, 0);
        accb[t] = __builtin_amdgcn_mfma_f32_16x16x32_bf16(
            h3, bs_read(Bs, 2, c, 3, quad), accb[t], 0, 0, 0);
    }

    const int gr0 = blockIdx.x * 128 + wave * 16 + quad * 4;
#pragma unroll
    for (int t = 0; t < 4; ++t) {
        int colg = t * 16 + m;
        float bv = bias[colg];
#pragma unroll
        for (int i = 0; i < 4; ++i) {
            int gr = gr0 + i;
            if (gr < N) {
                zf[(size_t)gr * 64 + colg] = accz[t][i] + bv;
                t08[(size_t)gr * 64 + colg] = f2fp8_1(acca[t][i]);
                t18[(size_t)gr * 64 + colg] = f2fp8_1(accb[t][i]);
            }
        }
    }
}

// ---- agg L2: quarter-wave per edge, fp8 64B rows, 16 edges/iter ---------
__global__ __launch_bounds__(256) void
agg2_kernel(const unsigned char* __restrict__ t08,
            const unsigned char* __restrict__ t18,
            const float* __restrict__ z2,
            const int* __restrict__ csr, const int* __restrict__ off,
            unsigned short* __restrict__ h2b, int N, int twoE)
{
    int w = blockIdx.x * 4 + (threadIdx.x >> 6);
    int lane = threadIdx.x & 63;
    if (w >= N) return;
    const int q = lane >> 4;                 // edge slot 0..3
    const int col = (lane & 15) * 4;         // 4 fp8 cols per lane
    const unsigned char* t0c = t08 + col;
    const unsigned char* t1c = t18 + col;

    float a0 = 0.f, a1 = 0.f, a2 = 0.f, a3 = 0.f;   // rel0
    float b0 = 0.f, b1 = 0.f, b2 = 0.f, b3 = 0.f;   // rel1

    // ---- relation 0 ----
    int o0 = RFL(off[w]);
    int o1 = RFL(off[w + 1]);
    int d0 = o1 - o0;
    int j = o0;
    for (; j + 15 < o1; j += 16) {
        int r0 = csr[j + q];
        int r1 = csr[j + 4 + q];
        int r2 = csr[j + 8 + q];
        int r3 = csr[j + 12 + q];
        unsigned v0 = *(const unsigned*)(t0c + (size_t)r0 * 64);
        unsigned v1 = *(const unsigned*)(t0c + (size_t)r1 * 64);
        unsigned v2 = *(const unsigned*)(t0c + (size_t)r2 * 64);
        unsigned v3 = *(const unsigned*)(t0c + (size_t)r3 * 64);
        floatx2 l0 = fp8lo(v0), h0 = fp8hi(v0);
        floatx2 l1 = fp8lo(v1), h1 = fp8hi(v1);
        floatx2 l2 = fp8lo(v2), h2 = fp8hi(v2);
        floatx2 l3 = fp8lo(v3), h3 = fp8hi(v3);
        a0 += (l0.x + l1.x) + (l2.x + l3.x);
        a1 += (l0.y + l1.y) + (l2.y + l3.y);
        a2 += (h0.x + h1.x) + (h2.x + h3.x);
        a3 += (h0.y + h1.y) + (h2.y + h3.y);
    }
    for (; j + 3 < o1; j += 4) {
        int r = csr[j + q];
        unsigned v = *(const unsigned*)(t0c + (size_t)r * 64);
        floatx2 l = fp8lo(v), h = fp8hi(v);
        a0 += l.x; a1 += l.y; a2 += h.x; a3 += h.y;
    }
    if (j < o1 && q < o1 - j) {
        int r = csr[j + q];
        unsigned v = *(const unsigned*)(t0c + (size_t)r * 64);
        floatx2 l = fp8lo(v), h = fp8hi(v);
        a0 += l.x; a1 += l.y; a2 += h.x; a3 += h.y;
    }

    // ---- relation 1 ----
    int p = N + w;
    o0 = RFL(off[p]);
    o1 = (p + 1 < 2 * N) ? RFL(off[p + 1]) : twoE;
    int d1 = o1 - o0;
    j = o0;
    for (; j + 15 < o1; j += 16) {
        int r0 = csr[j + q];
        int r1 = csr[j + 4 + q];
        int r2 = csr[j + 8 + q];
        int r3 = csr[j + 12 + q];
        unsigned v0 = *(const unsigned*)(t1c + (size_t)r0 * 64);
        unsigned v1 = *(const unsigned*)(t1c + (size_t)r1 * 64);
        unsigned v2 = *(const unsigned*)(t1c + (size_t)r2 * 64);
        unsigned v3 = *(const unsigned*)(t1c + (size_t)r3 * 64);
        floatx2 l0 = fp8lo(v0), h0 = fp8hi(v0);
        floatx2 l1 = fp8lo(v1), h1 = fp8hi(v1);
        floatx2 l2 = fp8lo(v2), h2 = fp8hi(v2);
        floatx2 l3 = fp8lo(v3), h3 = fp8hi(v3);
        b0 += (l0.x + l1.x) + (l2.x + l3.x);
        b1 += (l0.y + l1.y) + (l2.y + l3.y);
        b2 += (h0.x + h1.x) + (h2.x + h3.x);
        b3 += (h0.y + h1.y) + (h2.y + h3.y);
    }
    for (; j + 3 < o1; j += 4) {
        int r = csr[j + q];
        unsigned v = *(const unsigned*)(t1c + (size_t)r * 64);
        floatx2 l = fp8lo(v), h = fp8hi(v);
        b0 += l.x; b1 += l.y; b2 += h.x; b3 += h.y;
    }
    if (j < o1 && q < o1 - j) {
        int r = csr[j + q];
        unsigned v = *(const unsigned*)(t1c + (size_t)r * 64);
        floatx2 l = fp8lo(v), h = fp8hi(v);
        b0 += l.x; b1 += l.y; b2 += h.x; b3 += h.y;
    }

    // cross-quarter reduce + write
    a0 += __shfl_xor(a0, 16); a1 += __shfl_xor(a1, 16);
    a2 += __shfl_xor(a2, 16); a3 += __shfl_xor(a3, 16);
    b0 += __shfl_xor(b0, 16); b1 += __shfl_xor(b1, 16);
    b2 += __shfl_xor(b2, 16); b3 += __shfl_xor(b3, 16);
    a0 += __shfl_xor(a0, 32); a1 += __shfl_xor(a1, 32);
    a2 += __shfl_xor(a2, 32); a3 += __shfl_xor(a3, 32);
    b0 += __shfl_xor(b0, 32); b1 += __shfl_xor(b1, 32);
    b2 += __shfl_xor(b2, 32); b3 += __shfl_xor(b3, 32);
    if (q == 0) {
        float inv0 = 1.0f / fmaxf((float)d0, 1.0f);
        float inv1 = 1.0f / fmaxf((float)d1, 1.0f);
        float4 z = *(const float4*)(z2 + (size_t)w * 64 + col);
        float h0v = z.x + a0 * inv0 + b0 * inv1;
        float h1v = z.y + a1 * inv0 + b1 * inv1;
        float h2v = z.z + a2 * inv0 + b2 * inv1;
        float h3v = z.w + a3 * inv0 + b3 * inv1;
        uint2 u;
        u.x = pack2(h0v, h1v);
        u.y = pack2(h2v, h3v);
        *(uint2*)(h2b + (size_t)w * 64 + col) = u;
    }
}

// ---- score (merged pos+neg): 8 lanes/edge, 128B rows, shfl reduce --------
__global__ __launch_bounds__(256) void
score_kernel(const unsigned short* __restrict__ h, // [N,64] bf16
             const int* __restrict__ edges, const int* __restrict__ neg,
             float* __restrict__ out, int E, int En)
{
    int t = blockIdx.x * blockDim.x + threadIdx.x;
    int e = t >> 3;
    int c = t & 7;
    if (e >= E + En) return;
    int sI, dI, oI;
    if (e < E) { sI = edges[e]; dI = edges[E + e]; oI = e; }
    else { int en = e - E; sI = neg[en]; dI = neg[En + en]; oI = E + en; }
    uint4 va = *(const uint4*)(h + (size_t)sI * 64 + c * 8);
    uint4 vb = *(const uint4*)(h + (size_t)dI * 64 + c * 8);
    float s = 0.0f;
    s = fmaf(bflo(va.x), bflo(vb.x), s);
    s = fmaf(bfhi(va.x), bfhi(vb.x), s);
    s = fmaf(bflo(va.y), bflo(vb.y), s);
    s = fmaf(bfhi(va.y), bfhi(vb.y), s);
    s = fmaf(bflo(va.z), bflo(vb.z), s);
    s = fmaf(bfhi(va.z), bfhi(vb.z), s);
    s = fmaf(bflo(va.w), bflo(vb.w), s);
    s = fmaf(bfhi(va.w), bfhi(vb.w), s);
    s += __shfl_xor(s, 1);
    s += __shfl_xor(s, 2);
    s += __shfl_xor(s, 4);
    if (c == 0) out[oI] = s;
}

extern "C" void kernel_launch(void* const* d_in, const int* in_sizes, int n_in,
                              void* d_out, int out_size, void* d_ws, size_t ws_size,
                              hipStream_t stream)
{
    const float* x     = (const float*)d_in[0];
    const int*   edges = (const int*)d_in[1];
    const int*   neg   = (const int*)d_in[2];
    const float* Wn1   = (const float*)d_in[3];
    const float* Ws1   = (const float*)d_in[4];
    const float* b1    = (const float*)d_in[5];
    const float* Wn2   = (const float*)d_in[6];
    const float* Ws2   = (const float*)d_in[7];
    const float* b2    = (const float*)d_in[8];
    float* out = (float*)d_out;

    const int Fin = 128, R = 2;
    const int N  = in_sizes[0] / Fin;        // 50000
    const int E  = in_sizes[1] / (R * 2);    // 800000
    const int En = in_sizes[2] / 2;          // 800000
    const int twoE = 2 * E;
    const int NBK = (N + BW - 1) / BW;       // 391
    const int rbT = 2 * NBK;

    // ---- workspace layout (aliases noted) ----
    const size_t nb128 = (size_t)N * 128 * sizeof(unsigned short);   // 12.8MB
    char* p = (char*)d_ws;

    // region0: staging [2E] (CSR build) -> xb8 [N,128] fp8 (cvt..agg1)
    //          -> z2 [N,64] f32 (gemm2..agg2). Lifetimes strictly ordered.
    uint2* staging       = (uint2*)p;
    unsigned char* xb8   = (unsigned char*)p;
    float* z2            = (float*)p;
    {
        size_t r0 = (size_t)twoE * sizeof(uint2);          // 12.8MB
        size_t r1 = (size_t)N * 64 * sizeof(float);        // 12.8MB
        size_t r2 = (size_t)N * 128;                       // 6.4MB
        size_t rm = r0 > r1 ? r0 : r1;
        if (r2 > rm) rm = r2;
        p += rm;
    }
    unsigned short* m0  = (unsigned short*)p; p += nb128;  // [N,128] mean rel0 (t08/t18 reuse)
    unsigned short* m1  = (unsigned short*)p; p += nb128;  // [N,128] mean rel1 (h2b reuse)
    unsigned short* xb  = (unsigned short*)p; p += nb128;  // [N,128] bf16 x
    unsigned short* h1b = (unsigned short*)p; p += nb128;  // [N,128] bf16 h1
    unsigned short* WT1z = (unsigned short*)p; p += 16384 * 2;
    unsigned short* WT1a = (unsigned short*)p; p += 16384 * 2;
    unsigned short* WT1b = (unsigned short*)p; p += 16384 * 2;
    unsigned short* WT2z = (unsigned short*)p; p += 8192 * 2;
    unsigned short* WT2a = (unsigned short*)p; p += 8192 * 2;
    unsigned short* WT2b = (unsigned short*)p; p += 8192 * 2;
    float* bc1 = (float*)p; p += 128 * sizeof(float);
    float* bc2 = (float*)p; p += 64 * sizeof(float);
    int* bcnt = (int*)p; p += (size_t)2 * NBK_MAX * sizeof(int);
    int* gcur = (int*)p; p += (size_t)2 * NBK_MAX * sizeof(int);
    int* bko  = (int*)p; p += ((size_t)2 * NBK_MAX + 1) * sizeof(int);
    int* off  = (int*)p; p += (size_t)2 * N * sizeof(int);
    int* csr  = (int*)p;

    unsigned char*  t08 = (unsigned char*)m0;        // [N,64] fp8
    unsigned char*  t18 = t08 + (size_t)N * 64;      // [N,64] fp8
    unsigned short* h2b = m1;                        // [N,64] bf16

    const int BS = 256;
    const int edge_blocks = (twoE + EPB - 1) / EPB;
    const int gx128 = (N + 127) / 128;

    // ---- CSR build (radix by dst bucket) ----
    hipMemsetAsync(bcnt, 0, (size_t)4 * NBK_MAX * sizeof(int), stream);
    bucket_count_kernel<<<edge_blocks, BS, 0, stream>>>(edges, bcnt, NBK, E);
    bucket_scan_kernel<<<1, 1024, 0, stream>>>(bcnt, bko, rbT, twoE);
    partition_kernel<<<edge_blocks, BS, 0, stream>>>(edges, bko, gcur, staging, NBK, E);
    bucket_csr_kernel<<<rbT, BS, 0, stream>>>(staging, bko, csr, off, NBK, N);

    // ---- prep (cvt AFTER bucket_csr: xb8 aliases dead staging) ----
    cvt_kernel<<<(N * 32 + BS - 1) / BS, BS, 0, stream>>>(x, xb, xb8, N * 32);
    prep_kernel<<<(16384 + BS - 1) / BS, BS, 0, stream>>>(
        Ws1, Wn1, b1, Ws2, Wn2, b2,
        WT1z, WT1a, WT1b, bc1, WT2z, WT2a, WT2b, bc2);

    // ---- Layer 1: fp8 aggregate (vector-idx quarter-wave), fused GEMM ---
    agg1_kernel<<<(N + 3) / 4, BS, 0, stream>>>(xb8, csr, off, m0, m1, N, twoE);
    {
        dim3 g(gx128, 2);
        gemm1_fused_kernel<<<g, 512, 0, stream>>>(xb, m0, m1, WT1z, WT1a, WT1b,
                                                  bc1, h1b, N);
    }

    // ---- Layer 2: fused transform (z2 f32, t0/t1 fp8), quarter-wave agg -
    gemm2_fused_kernel<<<gx128, 512, 0, stream>>>(h1b, WT2z, WT2a, WT2b, bc2,
                                                  z2, t08, t18, N);
    agg2_kernel<<<(N + 3) / 4, BS, 0, stream>>>(t08, t18, z2, csr, off, h2b, N, twoE);

    // ---- Scores (pos + neg in one launch) ----
    score_kernel<<<((E + En) * 8 + BS - 1) / BS, BS, 0, stream>>>(
        h2b, edges, neg, out, E, En);
}